// Round 3
// baseline (338.362 us; speedup 1.0000x reference)
//
#include <hip/hip_runtime.h>
#include <cstdint>
#include <cstddef>

#define HIDDEN 256
#define NHEADS 8
#define HDIM 32
#define KLEN 8192
#define BATCH 32
#define NCHUNK 16
#define CHUNK (KLEN / NCHUNK)     // 512
#define NCHUNK_S 32
#define CROWS (KLEN / NCHUNK_S)   // 256
#define LN_EPS 1e-5f

// ---------------- workspace layout (float offsets) ----------------
#define OFF_QT   ((size_t)0)
#define SZ_QT    ((size_t)2*BATCH*NHEADS*HIDDEN)          // 131072
#define OFF_SC   (OFF_QT + SZ_QT)
#define SZ_SC    ((size_t)2*BATCH*KLEN*NHEADS)            // 4194304
#define OFF_UP   (OFF_SC + SZ_SC)
#define SZ_UP    ((size_t)2*BATCH*NCHUNK*NHEADS*HIDDEN)   // 2097152
#define OFF_COMB (OFF_UP + SZ_UP)
#define SZ_COMB  ((size_t)BATCH*2*HIDDEN)                 // 16384

// K1: qh = z_gene @ Wq^T (per b), then qtilde[m][b][n][h] = alpha * sum_d qh[n,d]*Wk_m[n*32+d, h]
__global__ void k_prep(const float* __restrict__ zg, const float* __restrict__ Wq,
                       const float* __restrict__ Wk0, const float* __restrict__ Wk1,
                       const float* __restrict__ log_temp, float* __restrict__ qt) {
    int b = blockIdx.x, t = threadIdx.x;
    __shared__ float z[HIDDEN];
    __shared__ float qh[HIDDEN];
    z[t] = zg[(size_t)b*HIDDEN + t];
    __syncthreads();
    const float4* wr4 = (const float4*)(Wq + (size_t)t*HIDDEN);
    const float4* z4 = (const float4*)z;
    float acc = 0.f;
    #pragma unroll 8
    for (int i = 0; i < HIDDEN/4; ++i) {
        float4 w = wr4[i], zz = z4[i];
        acc += w.x*zz.x + w.y*zz.y + w.z*zz.z + w.w*zz.w;
    }
    qh[t] = acc;
    __syncthreads();
    float alpha = 0.5f * rsqrtf((float)HDIM) * __expf(log_temp[0]);
    for (int m = 0; m < 2; ++m) {
        const float* Wk = m ? Wk1 : Wk0;
        for (int n = 0; n < NHEADS; ++n) {
            float a = 0.f;
            #pragma unroll 8
            for (int d = 0; d < HDIM; ++d) {
                a += qh[n*HDIM + d] * Wk[(size_t)(n*HDIM + d)*HIDDEN + t];
            }
            qt[(((size_t)m*BATCH + b)*NHEADS + n)*HIDDEN + t] = a * alpha;
        }
    }
}

// K2 v3: sc[m][b][k][n] = qtilde[m][b][n][:] . kv_m[b][k][:]
// 8-lane group handles 4 rows; lane seg owns strided float4 columns (i*8+seg).
// q from LDS, reused across 4 rows. acc[4 rows][8 heads] scalar.
// Transposing shfl reduce so lane seg ends holding head==seg.
__global__ void __launch_bounds__(256, 4) k_scores(const float* __restrict__ kv0,
                                                   const float* __restrict__ kv1,
                                                   const float* __restrict__ qt,
                                                   float* __restrict__ sc) {
    int bid = blockIdx.x;              // BATCH * 2 * NCHUNK_S = 2048
    int chunk = bid % NCHUNK_S;
    int m = (bid / NCHUNK_S) & 1;
    int b = bid / (2*NCHUNK_S);
    int t = threadIdx.x;
    int wave = t >> 6;
    int g    = (t >> 3) & 7;
    int seg  = t & 7;
    __shared__ float lq[NHEADS*260];   // padded stride 260
    const float* qtg = qt + ((size_t)m*BATCH + b)*NHEADS*HIDDEN;
    #pragma unroll
    for (int i = 0; i < 8; ++i) {
        int j = t + i*256;
        lq[(j >> 8)*260 + (j & 255)] = qtg[j];
    }
    __syncthreads();
    const float* kv = (m ? kv1 : kv0) + (size_t)b*KLEN*HIDDEN;
    const float4* kv4 = (const float4*)kv;
    float* out = sc + ((size_t)m*BATCH + b)*KLEN*NHEADS;
    int b0 = seg & 1, b1 = (seg >> 1) & 1, b2 = (seg >> 2) & 1;

    #pragma unroll
    for (int pass = 0; pass < 2; ++pass) {
        size_t r = (size_t)chunk*CROWS + wave*64 + pass*32 + g*4;
        float acc[4][8];
        #pragma unroll
        for (int j = 0; j < 4; ++j)
            #pragma unroll
            for (int n = 0; n < 8; ++n) acc[j][n] = 0.f;
        #pragma unroll 2
        for (int i = 0; i < 8; ++i) {
            int c = i*8 + seg;
            float4 k0 = kv4[(r+0)*64 + c];
            float4 k1 = kv4[(r+1)*64 + c];
            float4 k2 = kv4[(r+2)*64 + c];
            float4 k3 = kv4[(r+3)*64 + c];
            #pragma unroll
            for (int n = 0; n < 8; ++n) {
                float4 q = ((const float4*)(lq + n*260))[c];
                acc[0][n] += k0.x*q.x + k0.y*q.y + k0.z*q.z + k0.w*q.w;
                acc[1][n] += k1.x*q.x + k1.y*q.y + k1.z*q.z + k1.w*q.w;
                acc[2][n] += k2.x*q.x + k2.y*q.y + k2.z*q.z + k2.w*q.w;
                acc[3][n] += k3.x*q.x + k3.y*q.y + k3.z*q.z + k3.w*q.w;
            }
        }
        #pragma unroll
        for (int j = 0; j < 4; ++j) {
            float w[4];
            #pragma unroll
            for (int u = 0; u < 4; ++u) {
                float kkeep = b0 ? acc[j][2*u+1] : acc[j][2*u];
                float ksend = b0 ? acc[j][2*u]   : acc[j][2*u+1];
                w[u] = kkeep + __shfl_xor(ksend, 1);
            }
            float x[2];
            #pragma unroll
            for (int u = 0; u < 2; ++u) {
                float kkeep = b1 ? w[2*u+1] : w[2*u];
                float ksend = b1 ? w[2*u]   : w[2*u+1];
                x[u] = kkeep + __shfl_xor(ksend, 2);
            }
            float kkeep = b2 ? x[1] : x[0];
            float ksend = b2 ? x[0] : x[1];
            float y = kkeep + __shfl_xor(ksend, 4);
            out[(r+j)*8 + seg] = y;
        }
    }
}

// K3 v3: entmax tau by bisection, then write p = max(z-tau,0)^2 back into sc (own column)
__global__ void __launch_bounds__(256) k_entmax(float* __restrict__ sc) {
    int bid = blockIdx.x;              // m*256 + b*8 + n
    int n = bid & 7, b = (bid >> 3) & 31, m = bid >> 8;
    int t = threadIdx.x;
    __shared__ float zs[KLEN];
    __shared__ float red[4];
    float* src = sc + ((size_t)m*BATCH + b)*KLEN*NHEADS + n;
    float mx = -1e30f;
    #pragma unroll
    for (int i = 0; i < KLEN/256; ++i) {
        float v = src[(size_t)(t + i*256)*NHEADS];
        zs[t + i*256] = v;
        mx = fmaxf(mx, v);
    }
    for (int off = 32; off; off >>= 1) mx = fmaxf(mx, __shfl_xor(mx, off));
    if ((t & 63) == 0) red[t >> 6] = mx;
    __syncthreads();
    mx = fmaxf(fmaxf(red[0], red[1]), fmaxf(red[2], red[3]));
    __syncthreads();
    const float4* z4 = (const float4*)zs;
    float lo = mx - 1.0f, hi = mx;
    for (int it = 0; it < 26; ++it) {
        float tm = 0.5f*(lo + hi);
        float s = 0.f;
        #pragma unroll
        for (int i = 0; i < 8; ++i) {
            float4 zz = z4[t + i*256];
            float d;
            d = fmaxf(zz.x - tm, 0.f); s = fmaf(d, d, s);
            d = fmaxf(zz.y - tm, 0.f); s = fmaf(d, d, s);
            d = fmaxf(zz.z - tm, 0.f); s = fmaf(d, d, s);
            d = fmaxf(zz.w - tm, 0.f); s = fmaf(d, d, s);
        }
        for (int off = 32; off; off >>= 1) s += __shfl_xor(s, off);
        if ((t & 63) == 0) red[t >> 6] = s;
        __syncthreads();
        s = red[0] + red[1] + red[2] + red[3];
        __syncthreads();
        if (s >= 1.0f) lo = tm; else hi = tm;
    }
    float tfin = 0.5f*(lo + hi);
    #pragma unroll
    for (int i = 0; i < KLEN/256; ++i) {
        float d = fmaxf(zs[t + i*256] - tfin, 0.f);
        src[(size_t)(t + i*256)*NHEADS] = d*d;
    }
}

// K4 v3: u[m][b][n][h] partial sums per chunk, reading precomputed p from sc.
// 4 consecutive k per wave-iteration: 4 coalesced kv float4 + 8 uniform p float4
// + 128 FMA into acc[8 heads][4 cols]. Reverse block order for L3 reuse.
__global__ void __launch_bounds__(256, 4) k_ctxsum(const float* __restrict__ kv0,
                                                   const float* __restrict__ kv1,
                                                   const float* __restrict__ sc,
                                                   float* __restrict__ upart) {
    int bid = (int)gridDim.x - 1 - (int)blockIdx.x;   // reverse order for L3 hits
    int chunk = bid % NCHUNK;
    int m = (bid / NCHUNK) & 1;
    int b = bid / (2*NCHUNK);
    int t = threadIdx.x;
    int wave = t >> 6, lane = t & 63;
    const float* kv = (m ? kv1 : kv0) + (size_t)b*KLEN*HIDDEN;
    const float4* kv4 = (const float4*)kv;
    const float4* prow4 = (const float4*)(sc + ((size_t)m*BATCH + b)*KLEN*NHEADS);
    float acc[8][4];
    #pragma unroll
    for (int nn = 0; nn < 8; ++nn)
        #pragma unroll
        for (int c = 0; c < 4; ++c) acc[nn][c] = 0.f;

    for (int kb = wave*4; kb < CHUNK; kb += 16) {
        size_t k = (size_t)chunk*CHUNK + kb;
        float4 kva = kv4[(k+0)*64 + lane];
        float4 kvb = kv4[(k+1)*64 + lane];
        float4 kvc = kv4[(k+2)*64 + lane];
        float4 kvd = kv4[(k+3)*64 + lane];
        float4 pa0 = prow4[(k+0)*2], pa1 = prow4[(k+0)*2 + 1];
        float4 pb0 = prow4[(k+1)*2], pb1 = prow4[(k+1)*2 + 1];
        float4 pc0 = prow4[(k+2)*2], pc1 = prow4[(k+2)*2 + 1];
        float4 pd0 = prow4[(k+3)*2], pd1 = prow4[(k+3)*2 + 1];
        #define ACC4(P0, P1, KV) \
            acc[0][0] = fmaf(P0.x, KV.x, acc[0][0]); acc[0][1] = fmaf(P0.x, KV.y, acc[0][1]); \
            acc[0][2] = fmaf(P0.x, KV.z, acc[0][2]); acc[0][3] = fmaf(P0.x, KV.w, acc[0][3]); \
            acc[1][0] = fmaf(P0.y, KV.x, acc[1][0]); acc[1][1] = fmaf(P0.y, KV.y, acc[1][1]); \
            acc[1][2] = fmaf(P0.y, KV.z, acc[1][2]); acc[1][3] = fmaf(P0.y, KV.w, acc[1][3]); \
            acc[2][0] = fmaf(P0.z, KV.x, acc[2][0]); acc[2][1] = fmaf(P0.z, KV.y, acc[2][1]); \
            acc[2][2] = fmaf(P0.z, KV.z, acc[2][2]); acc[2][3] = fmaf(P0.z, KV.w, acc[2][3]); \
            acc[3][0] = fmaf(P0.w, KV.x, acc[3][0]); acc[3][1] = fmaf(P0.w, KV.y, acc[3][1]); \
            acc[3][2] = fmaf(P0.w, KV.z, acc[3][2]); acc[3][3] = fmaf(P0.w, KV.w, acc[3][3]); \
            acc[4][0] = fmaf(P1.x, KV.x, acc[4][0]); acc[4][1] = fmaf(P1.x, KV.y, acc[4][1]); \
            acc[4][2] = fmaf(P1.x, KV.z, acc[4][2]); acc[4][3] = fmaf(P1.x, KV.w, acc[4][3]); \
            acc[5][0] = fmaf(P1.y, KV.x, acc[5][0]); acc[5][1] = fmaf(P1.y, KV.y, acc[5][1]); \
            acc[5][2] = fmaf(P1.y, KV.z, acc[5][2]); acc[5][3] = fmaf(P1.y, KV.w, acc[5][3]); \
            acc[6][0] = fmaf(P1.z, KV.x, acc[6][0]); acc[6][1] = fmaf(P1.z, KV.y, acc[6][1]); \
            acc[6][2] = fmaf(P1.z, KV.z, acc[6][2]); acc[6][3] = fmaf(P1.z, KV.w, acc[6][3]); \
            acc[7][0] = fmaf(P1.w, KV.x, acc[7][0]); acc[7][1] = fmaf(P1.w, KV.y, acc[7][1]); \
            acc[7][2] = fmaf(P1.w, KV.z, acc[7][2]); acc[7][3] = fmaf(P1.w, KV.w, acc[7][3]);
        ACC4(pa0, pa1, kva)
        ACC4(pb0, pb1, kvb)
        ACC4(pc0, pc1, kvc)
        ACC4(pd0, pd1, kvd)
        #undef ACC4
    }
    // cross-wave reduce via LDS
    __shared__ float redls[4*NHEADS*HIDDEN];    // 32 KB
    float4* red4 = (float4*)redls;
    #pragma unroll
    for (int nn = 0; nn < 8; ++nn) {
        float4 v; v.x = acc[nn][0]; v.y = acc[nn][1]; v.z = acc[nn][2]; v.w = acc[nn][3];
        red4[((size_t)wave*8 + nn)*64 + lane] = v;
    }
    __syncthreads();
    float* up = upart + (((size_t)m*BATCH + b)*NCHUNK + chunk)*NHEADS*HIDDEN;
    int n = t >> 5, hq = (t & 31)*2;
    #pragma unroll
    for (int j = 0; j < 2; ++j) {
        float4 s = red4[((size_t)0*8 + n)*64 + hq + j];
        #pragma unroll
        for (int w = 1; w < 4; ++w) {
            float4 v = red4[((size_t)w*8 + n)*64 + hq + j];
            s.x += v.x; s.y += v.y; s.z += v.z; s.w += v.w;
        }
        ((float4*)(up + (size_t)n*HIDDEN))[hq + j] = s;
    }
}

// K5: reduce chunks, project through Wv, apply modality softmax weight, write combined
__global__ void k_ctx(const float* __restrict__ upart, const float* __restrict__ Wv0,
                      const float* __restrict__ Wv1, const float* __restrict__ mlogits,
                      float* __restrict__ comb) {
    int b = blockIdx.x, t = threadIdx.x;
    __shared__ float ul[NHEADS*260];
    float l0 = mlogits[0], l1 = mlogits[1];
    float mxl = fmaxf(l0, l1);
    float e0 = __expf(l0 - mxl), e1 = __expf(l1 - mxl);
    float w0 = e0/(e0 + e1), w1 = e1/(e0 + e1);
    for (int m = 0; m < 2; ++m) {
        const float* Wv = m ? Wv1 : Wv0;
        float wm = m ? w1 : w0;
        __syncthreads();
        for (int n = 0; n < NHEADS; ++n) {
            float s = 0.f;
            const float* up = upart + ((size_t)m*BATCH + b)*NCHUNK*NHEADS*HIDDEN
                              + (size_t)n*HIDDEN + t;
            #pragma unroll
            for (int c = 0; c < NCHUNK; ++c) s += up[(size_t)c*NHEADS*HIDDEN];
            ul[n*260 + t] = s;
        }
        __syncthreads();
        int n = t >> 5;   // t = n*32 + d
        const float4* wr4 = (const float4*)(Wv + (size_t)t*HIDDEN);
        const float4* uu4 = (const float4*)(ul + n*260);
        float acc = 0.f;
        #pragma unroll 8
        for (int i = 0; i < HIDDEN/4; ++i) {
            float4 w = wr4[i], uu = uu4[i];
            acc += w.x*uu.x + w.y*uu.y + w.z*uu.z + w.w*uu.w;
        }
        comb[(size_t)b*(2*HIDDEN) + (size_t)m*HIDDEN + t] = acc * wm;
    }
}

// K6: out = LayerNorm(comb @ Wout^T + b_out + z_gene)
__global__ void k_out(const float* __restrict__ comb, const float* __restrict__ Wout,
                      const float* __restrict__ bout, const float* __restrict__ zg,
                      const float* __restrict__ gamma, const float* __restrict__ beta,
                      float* __restrict__ out) {
    int b = blockIdx.x, t = threadIdx.x;
    __shared__ float cl[2*HIDDEN];
    __shared__ float red[4];
    cl[t] = comb[(size_t)b*512 + t];
    cl[t + 256] = comb[(size_t)b*512 + 256 + t];
    __syncthreads();
    float acc = bout[t] + zg[(size_t)b*HIDDEN + t];
    const float4* wr4 = (const float4*)(Wout + (size_t)t*512);
    const float4* cl4 = (const float4*)cl;
    #pragma unroll 8
    for (int i = 0; i < 512/4; ++i) {
        float4 w = wr4[i], c = cl4[i];
        acc += w.x*c.x + w.y*c.y + w.z*c.z + w.w*c.w;
    }
    float s = acc;
    for (int off = 32; off; off >>= 1) s += __shfl_xor(s, off);
    if ((t & 63) == 0) red[t >> 6] = s;
    __syncthreads();
    float mu = (red[0] + red[1] + red[2] + red[3]) * (1.0f/HIDDEN);
    __syncthreads();
    float dv = acc - mu;
    float vs = dv*dv;
    for (int off = 32; off; off >>= 1) vs += __shfl_xor(vs, off);
    if ((t & 63) == 0) red[t >> 6] = vs;
    __syncthreads();
    float var = (red[0] + red[1] + red[2] + red[3]) * (1.0f/HIDDEN);
    out[(size_t)b*HIDDEN + t] = dv * rsqrtf(var + LN_EPS) * gamma[t] + beta[t];
}

extern "C" void kernel_launch(void* const* d_in, const int* in_sizes, int n_in,
                              void* d_out, int out_size, void* d_ws, size_t ws_size,
                              hipStream_t stream) {
    const float* zg    = (const float*)d_in[0];
    const float* cpg   = (const float*)d_in[1];
    const float* mir   = (const float*)d_in[2];
    const float* Wq    = (const float*)d_in[3];
    const float* Wk0   = (const float*)d_in[4];
    const float* Wv0   = (const float*)d_in[5];
    const float* Wk1   = (const float*)d_in[6];
    const float* Wv1   = (const float*)d_in[7];
    const float* Wout  = (const float*)d_in[8];
    const float* bout  = (const float*)d_in[9];
    const float* gam   = (const float*)d_in[10];
    const float* bet   = (const float*)d_in[11];
    const float* mlog  = (const float*)d_in[12];
    const float* ltemp = (const float*)d_in[13];

    float* ws   = (float*)d_ws;
    float* qt   = ws + OFF_QT;
    float* sc   = ws + OFF_SC;
    float* up   = ws + OFF_UP;
    float* comb = ws + OFF_COMB;
    float* out  = (float*)d_out;

    hipLaunchKernelGGL(k_prep,   dim3(BATCH),             dim3(256), 0, stream,
                       zg, Wq, Wk0, Wk1, ltemp, qt);
    hipLaunchKernelGGL(k_scores, dim3(BATCH*2*NCHUNK_S),  dim3(256), 0, stream,
                       cpg, mir, qt, sc);
    hipLaunchKernelGGL(k_entmax, dim3(2*BATCH*NHEADS),    dim3(256), 0, stream,
                       sc);
    hipLaunchKernelGGL(k_ctxsum, dim3(BATCH*2*NCHUNK),    dim3(256), 0, stream,
                       cpg, mir, sc, up);
    hipLaunchKernelGGL(k_ctx,    dim3(BATCH),             dim3(256), 0, stream,
                       up, Wv0, Wv1, mlog, comb);
    hipLaunchKernelGGL(k_out,    dim3(BATCH),             dim3(256), 0, stream,
                       comb, Wout, bout, zg, gam, bet, out);
}